// Round 14
// baseline (72112.103 us; speedup 1.0000x reference)
//
#include <hip/hip_runtime.h>
#include <stdint.h>

#define BATCH 256
#define SEQT  512
#define DIM   128
#define HID   256
#define G3    768   // 3*HID
#define SBUF  8     // ring buffers per wave (1KB each)
#define SDEPTH 6    // async loads in flight per wave

typedef unsigned short u16;
typedef unsigned int   u32;
typedef _Float16 f16;
typedef f16 f16x2 __attribute__((ext_vector_type(2)));
typedef u32 u32x4v __attribute__((ext_vector_type(4)));

static __device__ __forceinline__ u16 f2h(float f) {
  f16 h = (f16)f; return __builtin_bit_cast(u16, h);
}
static __device__ __forceinline__ float h2f(u16 u) {
  return (float)__builtin_bit_cast(f16, u);
}
static __device__ __forceinline__ float sigm(float v) {
  return 1.f / (1.f + __expf(-v));
}

// 2-MAC f16 dot with f32 accumulate
static __device__ __forceinline__ float dot2f(u32 a, u32 b, float acc) {
#if __has_builtin(__builtin_amdgcn_fdot2)
  return __builtin_amdgcn_fdot2(__builtin_bit_cast(f16x2, a),
                                __builtin_bit_cast(f16x2, b), acc, false);
#else
  f16x2 av = __builtin_bit_cast(f16x2, a), bv = __builtin_bit_cast(f16x2, b);
  return acc + (float)av[0] * (float)bv[0] + (float)av[1] * (float)bv[1];
#endif
}
// 8 MACs, dual accumulator
static __device__ __forceinline__ void dot8q(float& a0, float& a1, u32x4v w, u32x4v a) {
  a0 = dot2f(w.x, a.x, a0);
  a1 = dot2f(w.y, a.y, a1);
  a0 = dot2f(w.z, a.z, a0);
  a1 = dot2f(w.w, a.w, a1);
}

// async 16B global -> LDS (per-lane global addr; LDS dest = wave-uniform base + lane*16)
static __device__ __forceinline__ void gload16(const u16* g, u16* l) {
  __builtin_amdgcn_global_load_lds(
      (const __attribute__((address_space(1))) u32*)g,
      (__attribute__((address_space(3))) u32*)l, 16, 0, 0);
}

// ---------------- weight fp32 -> f16, chunk-major transpose ----------------
// dst[((q*chunks + j)*256 + c)*8 + e] = f16( src[(q*256+c)*IN + j*8 + e] )
__global__ void convertT(const float* __restrict__ src, u16* __restrict__ dst,
                         int IN, int chunks, int total) {
  int t = blockIdx.x * 256 + threadIdx.x;
  if (t >= total) return;
  int e = t & 7, c = (t >> 3) & 255, r = t >> 11;
  int j = r % chunks, q = r / chunks;
  dst[t] = f2h(src[(size_t)(q * 256 + c) * IN + j * 8 + e]);
}

// ---------------- phase B: memory GRU, 768 threads, one block per batch row (round-6) ----------------
__launch_bounds__(768)
__global__ void gru_memk(const float* __restrict__ x,
                         const u16* __restrict__ WiT, const u16* __restrict__ WhT,
                         const float* __restrict__ bmi, const float* __restrict__ bmh,
                         u16* __restrict__ mem) {
  const int b = blockIdx.x, tid = threadIdx.x;
  const int q = tid >> 8, c = tid & 255;
  __shared__ __align__(16) u16 xsH[DIM];
  __shared__ __align__(16) u16 hsH[HID];
  __shared__ __align__(16) float rs[HID], zs[HID];

  float Brz = 0.f, Bni = 0.f, Bnh = 0.f;
  if (q < 2) { int rw = q * HID + c; Brz = bmi[rw] + bmh[rw]; }
  else       { int rw = 2 * HID + c; Bni = bmi[rw]; Bnh = bmh[rw]; }
  const u32x4v* wi = (const u32x4v*)WiT + (size_t)q * (DIM / 8) * 256 + c;
  const u32x4v* wh = (const u32x4v*)WhT + (size_t)q * (HID / 8) * 256 + c;
  float hprev = 0.f;
  if (tid < HID) hsH[tid] = 0;
  __syncthreads();

  for (int t = 0; t < SEQT; ++t) {
    if (tid < DIM)
      xsH[tid] = f2h(__builtin_nontemporal_load(x + ((size_t)b * SEQT + t) * DIM + tid));
    __syncthreads();               // xsH ready; hsH stable
    float ax0 = 0.f, ax1 = 0.f, ah0 = 0.f, ah1 = 0.f;
    {
      const u32x4v* xa = (const u32x4v*)xsH;
      const u32x4v* ha = (const u32x4v*)hsH;
      #pragma unroll 4
      for (int j = 0; j < DIM / 8; ++j) dot8q(ax0, ax1, wi[(size_t)j * 256], xa[j]);
      #pragma unroll 4
      for (int j = 0; j < HID / 8; ++j) dot8q(ah0, ah1, wh[(size_t)j * 256], ha[j]);
    }
    float ax = ax0 + ax1, ah = ah0 + ah1;
    if (q < 2) (q ? zs : rs)[c] = sigm(ax + ah + Brz);
    __syncthreads();               // rs/zs ready; hsH reads done
    if (q == 2) {
      float nn = tanhf(ax + Bni + rs[c] * (ah + Bnh));
      float h = (1.f - zs[c]) * nn + zs[c] * hprev;
      hprev = h;
      hsH[c] = f2h(h);
      mem[((size_t)b * SEQT + t) * HID + c] = f2h(h);
    }
    __syncthreads();               // hsH ready
  }
}

// ---------------- decoder cell: async LDS-staged weights, depth-6 vmcnt pipeline ----------------
template <int IN>
static __device__ __forceinline__ void cellL(const u16* __restrict__ inH,
                                             u16* __restrict__ outH,
                                             const u16* __restrict__ WT,
                                             int q, int c, int wid, int lane,
                                             float Brz, float Bni, float Bnh,
                                             float* __restrict__ rs, float* __restrict__ zs,
                                             u16 (* __restrict__ stg)[SBUF][512]) {
  constexpr int CH = IN / 8;       // 48 (cell0) or 32 weight chunks per gate row
  float a0 = 0.f, a1 = 0.f;
  if (q < 3) {
    const u16* wb = WT + ((size_t)q * CH * 256 + c) * 8;   // per-lane global base
    const u32x4v* av = (const u32x4v*)inH;
    u16* sb = &stg[wid][0][0];                             // wave-uniform LDS base
    asm volatile("s_waitcnt vmcnt(0)" ::: "memory");       // isolate stray vmem
    #pragma unroll
    for (int d = 0; d < SDEPTH; ++d)
      gload16(wb + (size_t)d * 2048, sb + d * 512);
    #pragma unroll
    for (int j = 0; j < CH; ++j) {
      const int issued = (j + SDEPTH < CH) ? (j + SDEPTH) : CH;
      asm volatile("s_waitcnt vmcnt(%0)" :: "i"(issued - (j + 1)) : "memory");
      u32x4v wv = *(const u32x4v*)(sb + (j & (SBUF - 1)) * 512 + lane * 8);
      dot8q(a0, a1, wv, av[j]);
      if (j + SDEPTH < CH)
        gload16(wb + (size_t)(j + SDEPTH) * 2048, sb + ((j + SDEPTH) & (SBUF - 1)) * 512);
    }
    if (q < 2) (q ? zs : rs)[c] = sigm(a0 + a1 + Brz);
  }
  __syncthreads();                 // rs/zs ready
  if (q == 2)
    outH[c] = f2h((1.f - zs[c]) * tanhf(a0 + a1 + Bni + rs[c] * Bnh));
  __syncthreads();                 // outH ready
}

// ---------------- phase C: decoder scan, 1024 threads, one block per batch row ----------------
__launch_bounds__(1024)
__global__ void decoderk(const float* __restrict__ x, const u16* __restrict__ memH,
                         const u16* __restrict__ W0T, const u16* __restrict__ W1T,
                         const u16* __restrict__ W2T, const u16* __restrict__ W3T,
                         const u16* __restrict__ W4T,
                         const float* __restrict__ bi0, const float* __restrict__ bh0,
                         const float* __restrict__ bi1, const float* __restrict__ bh1,
                         const float* __restrict__ bi2, const float* __restrict__ bh2,
                         const float* __restrict__ bi3, const float* __restrict__ bh3,
                         const float* __restrict__ bi4, const float* __restrict__ bh4,
                         const float* __restrict__ Wo, const float* __restrict__ bo,
                         float* __restrict__ out) {
  const int b = blockIdx.x, tid = threadIdx.x;
  const int lane = tid & 63, wave = tid >> 6;
  const int q = tid >> 8, c = tid & 255;
  __shared__ __align__(16) u16 kstH[HID];
  __shared__ __align__(16) u16 dvH[DIM + HID];
  __shared__ __align__(16) u16 hAH[HID], hBH[HID];
  __shared__ __align__(16) float rs[HID], zs[HID];
  __shared__ __align__(16) float ppF[512];
  __shared__ __align__(16) float pvp[8][HID];
  __shared__ float red[16], red2[16];
  __shared__ __align__(16) u16 wstage[16][SBUF][512];   // 128 KB async weight ring

  float Brz[5] = {0,0,0,0,0}, Bni[5] = {0,0,0,0,0}, Bnh[5] = {0,0,0,0,0};
  if (q < 2) {
    int rw = q * HID + c;
    Brz[0] = bi0[rw] + bh0[rw]; Brz[1] = bi1[rw] + bh1[rw]; Brz[2] = bi2[rw] + bh2[rw];
    Brz[3] = bi3[rw] + bh3[rw]; Brz[4] = bi4[rw] + bh4[rw];
  } else if (q == 2) {
    int rw = 2 * HID + c;
    Bni[0] = bi0[rw]; Bnh[0] = bh0[rw]; Bni[1] = bi1[rw]; Bnh[1] = bh1[rw];
    Bni[2] = bi2[rw]; Bnh[2] = bh2[rw]; Bni[3] = bi3[rw]; Bnh[3] = bh3[rw];
    Bni[4] = bi4[rw]; Bnh[4] = bh4[rw];
  }
  float wo0 = 0.f, wo1 = 0.f, wo2 = 0.f, wo3 = 0.f;
  const float bo0 = bo[0];
  if (wave == 0) { wo0 = Wo[lane]; wo1 = Wo[64+lane]; wo2 = Wo[128+lane]; wo3 = Wo[192+lane]; }
  if (tid < HID) kstH[tid] = 0;
  __syncthreads();

  const u16* mb = memH + (size_t)b * SEQT * HID;
  const int p = tid >> 1, hf = tid & 1;      // scores
  const int sg = tid >> 7, cp = tid & 127;   // PV

  for (int t = 0; t < SEQT; ++t) {
    float xr = 0.f;
    if (tid < DIM)
      xr = __builtin_nontemporal_load(x + ((size_t)b * SEQT + t) * DIM + tid);

    // ---- scores: thread = (position p, half hf) ----
    float s0 = 0.f, s1 = 0.f;
    {
      const u32x4v* mr = (const u32x4v*)(mb + (size_t)p * HID) + hf * 16;
      const u32x4v* kq = ((const u32x4v*)kstH) + hf * 16;
      u32x4v mA[8], mB[8];
      #pragma unroll
      for (int g = 0; g < 8; ++g) mA[g] = mr[g];
      #pragma unroll
      for (int g = 0; g < 8; ++g) mB[g] = mr[8 + g];
      #pragma unroll
      for (int g = 0; g < 8; ++g) dot8q(s0, s1, mA[g], kq[g]);
      #pragma unroll
      for (int g = 0; g < 8; ++g) dot8q(s0, s1, mB[g], kq[8 + g]);
    }
    float s = s0 + s1;
    s += __shfl_xor(s, 1);
    float mloc = s;
    #pragma unroll
    for (int off = 32; off; off >>= 1) mloc = fmaxf(mloc, __shfl_xor(mloc, off));
    if (lane == 0) red[wave] = mloc;
    __syncthreads();               // S1: red
    float m = red[0];
    #pragma unroll
    for (int i = 1; i < 16; ++i) m = fmaxf(m, red[i]);
    float pw = __expf(s - m);
    if (!hf) ppF[p] = pw;
    float ls = hf ? 0.f : pw;
    #pragma unroll
    for (int off = 32; off; off >>= 1) ls += __shfl_xor(ls, off);
    if (lane == 0) red2[wave] = ls;
    if (tid < DIM) dvH[tid] = f2h(xr);
    __syncthreads();               // S2: ppF, red2, dv-x

    // ---- PV: thread = (s-eighth sg, column pair cp); coalesced global reads ----
    float c0 = 0.f, c1 = 0.f;
    {
      const u32* mc = (const u32*)mb + (size_t)sg * 64 * 128 + cp;
      const float* ppg = ppF + sg * 64;
      #pragma unroll 8
      for (int pj = 0; pj < 64; ++pj) {
        u32 v = mc[(size_t)pj * 128];
        float w2 = ppg[pj];
        f16x2 hv = __builtin_bit_cast(f16x2, v);
        c0 += w2 * (float)hv[0];
        c1 += w2 * (float)hv[1];
      }
      pvp[sg][2 * cp]     = c0;
      pvp[sg][2 * cp + 1] = c1;
    }
    __syncthreads();               // S3: pvp
    if (tid < HID) {
      float lsum = red2[0];
      #pragma unroll
      for (int i = 1; i < 16; ++i) lsum += red2[i];
      float ctx = pvp[0][tid] + pvp[1][tid] + pvp[2][tid] + pvp[3][tid] +
                  pvp[4][tid] + pvp[5][tid] + pvp[6][tid] + pvp[7][tid];
      dvH[DIM + tid] = f2h(ctx / lsum);
    }
    __syncthreads();               // S4: dv complete

    // ---- 5 feed-forward GRU cells (async-staged weights) ----
    cellL<DIM + HID>(dvH, hAH, W0T, q, c, wave, lane, Brz[0], Bni[0], Bnh[0], rs, zs, wstage);
    cellL<HID>(hAH, hBH, W1T, q, c, wave, lane, Brz[1], Bni[1], Bnh[1], rs, zs, wstage);
    cellL<HID>(hBH, hAH, W2T, q, c, wave, lane, Brz[2], Bni[2], Bnh[2], rs, zs, wstage);
    cellL<HID>(hAH, hBH, W3T, q, c, wave, lane, Brz[3], Bni[3], Bnh[3], rs, zs, wstage);
    cellL<HID>(hBH, kstH, W4T, q, c, wave, lane, Brz[4], Bni[4], Bnh[4], rs, zs, wstage);

    // ---- output layer (wave 0) ----
    if (wave == 0) {
      float acc = h2f(kstH[lane]) * wo0 + h2f(kstH[64 + lane]) * wo1 +
                  h2f(kstH[128 + lane]) * wo2 + h2f(kstH[192 + lane]) * wo3;
      #pragma unroll
      for (int off = 32; off; off >>= 1) acc += __shfl_xor(acc, off);
      if (lane == 0) out[(size_t)b * SEQT + t] = sigm(acc + bo0);
    }
  }
}

// ---------------- host ----------------
extern "C" void kernel_launch(void* const* d_in, const int* in_sizes, int n_in,
                              void* d_out, int out_size, void* d_ws, size_t ws_size,
                              hipStream_t stream) {
  const float* x    = (const float*)d_in[0];
  const float* Wmi  = (const float*)d_in[1];
  const float* Wmh  = (const float*)d_in[2];
  const float* bmi  = (const float*)d_in[3];
  const float* bmh  = (const float*)d_in[4];
  const float* Wd0  = (const float*)d_in[5];
  const float* bi0  = (const float*)d_in[6];
  const float* bh0  = (const float*)d_in[7];
  const float* Wd1  = (const float*)d_in[8];
  const float* bi1  = (const float*)d_in[9];
  const float* bh1  = (const float*)d_in[10];
  const float* Wd2  = (const float*)d_in[11];
  const float* bi2  = (const float*)d_in[12];
  const float* bh2  = (const float*)d_in[13];
  const float* Wk0  = (const float*)d_in[14];
  const float* bik0 = (const float*)d_in[15];
  const float* bhk0 = (const float*)d_in[16];
  const float* Wk1  = (const float*)d_in[17];
  const float* bik1 = (const float*)d_in[18];
  const float* bhk1 = (const float*)d_in[19];
  const float* Wo   = (const float*)d_in[20];
  const float* bo   = (const float*)d_in[21];

  u16* mem = (u16*)d_ws;
  size_t off = (size_t)BATCH * SEQT * HID;     // u16 units
  u16* WmiT = mem + off; off += (size_t)G3 * DIM;
  u16* WmhT = mem + off; off += (size_t)G3 * HID;
  u16* W0T  = mem + off; off += (size_t)G3 * (DIM + HID);
  u16* W1T  = mem + off; off += (size_t)G3 * HID;
  u16* W2T  = mem + off; off += (size_t)G3 * HID;
  u16* W3T  = mem + off; off += (size_t)G3 * HID;
  u16* W4T  = mem + off; off += (size_t)G3 * HID;
  (void)ws_size; (void)in_sizes; (void)n_in; (void)out_size;

  // chunk-major f16 weight transposes
  convertT<<<(G3*DIM + 255) / 256, 256, 0, stream>>>(Wmi, WmiT, DIM, DIM/8, G3*DIM);
  convertT<<<(G3*HID + 255) / 256, 256, 0, stream>>>(Wmh, WmhT, HID, HID/8, G3*HID);
  convertT<<<(G3*(DIM+HID) + 255) / 256, 256, 0, stream>>>(Wd0, W0T, DIM+HID, (DIM+HID)/8, G3*(DIM+HID));
  convertT<<<(G3*HID + 255) / 256, 256, 0, stream>>>(Wd1, W1T, HID, HID/8, G3*HID);
  convertT<<<(G3*HID + 255) / 256, 256, 0, stream>>>(Wd2, W2T, HID, HID/8, G3*HID);
  convertT<<<(G3*HID + 255) / 256, 256, 0, stream>>>(Wk0, W3T, HID, HID/8, G3*HID);
  convertT<<<(G3*HID + 255) / 256, 256, 0, stream>>>(Wk1, W4T, HID, HID/8, G3*HID);

  gru_memk<<<BATCH, 768, 0, stream>>>(x, WmiT, WmhT, bmi, bmh, mem);
  decoderk<<<BATCH, 1024, 0, stream>>>(x, mem, W0T, W1T, W2T, W3T, W4T,
                                       bi0, bh0, bi1, bh1, bi2, bh2,
                                       bik0, bhk0, bik1, bhk1, Wo, bo,
                                       (float*)d_out);
}